// Round 9
// baseline (221.384 us; speedup 1.0000x reference)
//
#include <hip/hip_runtime.h>
#include <stdint.h>
#include <type_traits>

#define M_DIM 16384
#define N_DIM 2048
#define K_DIM 2048

typedef __bf16 bf16_t;
typedef __bf16 bf16x8 __attribute__((ext_vector_type(8)));
typedef __bf16 bf16x4 __attribute__((ext_vector_type(4)));
typedef float f32x4 __attribute__((ext_vector_type(4)));

template <int N> using ic = std::integral_constant<int, N>;

__device__ __forceinline__ void gload_lds16(const void* g, void* l) {
  __builtin_amdgcn_global_load_lds(
      (const __attribute__((address_space(1))) void*)g,
      (__attribute__((address_space(3))) void*)l, 16, 0, 0);
}

// float -> bf16 (RNE). SIGN applies sign() first (exact in bf16).
template <bool SIGN>
__global__ void cvt_kernel(const float* __restrict__ in, bf16_t* __restrict__ out) {
  long long i = ((long long)blockIdx.x * 256 + threadIdx.x) * 8;
  const float4* p = (const float4*)(in + i);
  float4 v0 = p[0];
  float4 v1 = p[1];
  float f[8] = {v0.x, v0.y, v0.z, v0.w, v1.x, v1.y, v1.z, v1.w};
  bf16x8 r;
#pragma unroll
  for (int j = 0; j < 8; ++j) {
    float v = f[j];
    if (SIGN) v = (v > 0.f) ? 1.f : ((v < 0.f) ? -1.f : 0.f);
    r[j] = (bf16_t)v;
  }
  *(bf16x8*)(out + i) = r;
}

// ============================================================================
// Round-9: B DIRECT GLOBAL->REG (no LDS for B), A in 3-slot LDS ring (96KB).
// 256x256 tile, BK=64, 8 waves (2Mx4N, 128x64/wave).
//  - B-frags loaded straight from global with 1-tile prefetch into
//    bfr[t&1][nt][k2]; per load: 16 rows x one 64B line, L2/L3-resident
//    (B total = 8 MB). Compiler auto-inserts counted vmcnt before use.
//  - A staged via gload_lds into slot t%3 (stage t+2 at tile t -> slot
//    (t+2)%3 != reading slot t%3; readers of (t+2)%3 were tile t-1's,
//    retired via MFMA data-deps before BAR(t) -> WAR safe with ONE barrier).
//  - Per tile: BAR; issue B(t+1)[8]; stage A(t+2)[4]; vmcnt(12) [leaves
//    exactly those 12 in flight -> drains stageA(t+1) (collective before
//    BAR(t+1)) and B(t)]; read aLo[8]; MFMA Qlow[32]; read aH[8];
//    MFMA Qhigh[32]. All lgkm waits compiler-counted -> LDS streams
//    under MFMA. LDS/tile = 1536 cy < MFMA 2483 cy.
//  - A swizzle unchanged from verified rounds 5-8: phys_col = col ^
//    ((row&7)<<4); linear gload_lds dest + inverse-swizzled global src.
// ============================================================================
__global__ __launch_bounds__(512, 2) void gemm_bg(const bf16_t* __restrict__ A,
                                                  const bf16_t* __restrict__ B,
                                                  const float* __restrict__ alpha_p,
                                                  float* __restrict__ C) {
  extern __shared__ char smem[];  // 3 slots x 32 KB (A tiles: 256 x 64 bf16)

  const int tid = threadIdx.x;
  const int lane = tid & 63;
  const int wid = tid >> 6;
  const int wm = wid >> 2;   // 0..1 -> rows wm*128..+127
  const int wn = wid & 3;    // 0..3 -> cols wn*64..+63

  // XCD-aware bijective swizzle (512 blocks, 512 % 8 == 0)
  const int bid = blockIdx.x;
  const int swz = (bid & 7) * 64 + (bid >> 3);
  const int bm = swz >> 3;   // 0..63
  const int bn = swz & 7;    // 0..7

  const int q = lane >> 4;   // 16B col-slot within K
  const int r15 = lane & 15; // frag row

  // ---- A fragment LDS byte bases (+ slot*32768 + mt*2048 immediates) ----
  const int swc = (r15 & 7) << 4;
  int aoff[2];
#pragma unroll
  for (int k = 0; k < 2; ++k)
    aoff[k] = (wm * 128 + r15) * 128 + ((k * 64 + q * 16) ^ swc);

  // ---- A stage pointers: inverse-swizzled global src, linear LDS dest ----
  const char* asrc0;
  {
    int P = tid * 16;
    int row = P >> 7;
    int lcol = (P & 127) ^ ((row & 7) << 4);
    asrc0 = (const char*)A + (size_t)(bm * 256 + row) * (K_DIM * 2) + lcol;
  }
  const int dsto = wid * 1024;

  // ---- B per-lane global pointers, one per nt (advance +768 per window) ----
  // B-frag[lane][j] = B[N = bn*256+wn*64+nt*16+(l&15)][K = t*64+k2*32+(l>>4)*8+j]
  const char* baddr[4];
#pragma unroll
  for (int nt = 0; nt < 4; ++nt)
    baddr[nt] = (const char*)B +
                (size_t)(bn * 256 + wn * 64 + nt * 16 + r15) * (K_DIM * 2) +
                q * 16;

  f32x4 acc[8][4];
#pragma unroll
  for (int mt = 0; mt < 8; ++mt)
#pragma unroll
    for (int nt = 0; nt < 4; ++nt) acc[mt][nt] = (f32x4){0.f, 0.f, 0.f, 0.f};

  bf16x8 bfr[2][4][2];  // [t&1][nt][k2]

  // ---- Prologue: stage A(0)->slot0, A(1)->slot1; load B(0); vmcnt(12) ----
#pragma unroll
  for (int t = 0; t < 2; ++t)
#pragma unroll
    for (int j = 0; j < 4; ++j)
      gload_lds16(asrc0 + (size_t)j * 262144 + t * 128,
                  smem + t * 32768 + j * 8192 + dsto);
#pragma unroll
  for (int nt = 0; nt < 4; ++nt)
#pragma unroll
    for (int k2 = 0; k2 < 2; ++k2)
      bfr[0][nt][k2] = *(const bf16x8*)(baddr[nt] + k2 * 64);
  asm volatile("s_waitcnt vmcnt(12)" ::: "memory");  // A(0) staged

  // One K-tile. U = in-window index (0..5): slot = U%3, parity = U&1.
  // MODE: 0 steady; 1 = t=30 (no stage, prefetch B(31), vmcnt(8));
  //       2 = t=31 (no issues, vmcnt(0)).
  auto kstep = [&](auto UC, auto MC) {
    constexpr int U = UC.value;
    constexpr int MODE = MC.value;
    constexpr int SLOT = (U % 3) * 32768;
    constexpr int PSLOT = ((U + 2) % 3) * 32768;
    constexpr int GOFF = (U + 2) * 128;
    constexpr int BOFF = (U + 1) * 128;
    constexpr int PAR = U & 1;

    __builtin_amdgcn_s_barrier();   // slot(t) collectively valid; WAR gate

    // Issue B(t+1) prefetch (8 global_load_dwordx4; no use until next tile)
    if constexpr (MODE != 2) {
#pragma unroll
      for (int nt = 0; nt < 4; ++nt)
#pragma unroll
        for (int k2 = 0; k2 < 2; ++k2)
          bfr[PAR ^ 1][nt][k2] =
              *(const bf16x8*)(baddr[nt] + BOFF + k2 * 64);
    }
    // Stage A(t+2) -> slot (t+2)%3 (readers were tile t-1, retired pre-BAR)
    if constexpr (MODE == 0) {
#pragma unroll
      for (int j = 0; j < 4; ++j)
        gload_lds16(asrc0 + (size_t)j * 262144 + GOFF,
                    smem + PSLOT + j * 8192 + dsto);
    }
    // Counted drain: leave only B(t+1)+stageA(t+2) in flight ->
    // stageA(t+1) drained (collective before BAR(t+1)) and B(t) drained.
    if constexpr (MODE == 0) {
      asm volatile("s_waitcnt vmcnt(12)" ::: "memory");
    } else if constexpr (MODE == 1) {
      asm volatile("s_waitcnt vmcnt(8)" ::: "memory");
    } else {
      asm volatile("s_waitcnt vmcnt(0)" ::: "memory");
    }

    bf16x8 a[4][2];
    // aLo reads + Qlow (compiler-counted lgkm; reads stream under MFMA)
#pragma unroll
    for (int mt = 0; mt < 4; ++mt)
#pragma unroll
      for (int k = 0; k < 2; ++k)
        a[mt][k] = *(const bf16x8*)(smem + SLOT + aoff[k] + mt * 2048);
#pragma unroll
    for (int k = 0; k < 2; ++k)
#pragma unroll
      for (int mt = 0; mt < 4; ++mt)
#pragma unroll
        for (int nt = 0; nt < 4; ++nt)
          acc[mt][nt] = __builtin_amdgcn_mfma_f32_16x16x32_bf16(
              a[mt][k], bfr[PAR][nt][k], acc[mt][nt], 0, 0, 0);
    // aH reads + Qhigh
#pragma unroll
    for (int mt = 0; mt < 4; ++mt)
#pragma unroll
      for (int k = 0; k < 2; ++k)
        a[mt][k] = *(const bf16x8*)(smem + SLOT + aoff[k] + (4 + mt) * 2048);
#pragma unroll
    for (int k = 0; k < 2; ++k)
#pragma unroll
      for (int mt = 0; mt < 4; ++mt)
#pragma unroll
        for (int nt = 0; nt < 4; ++nt)
          acc[4 + mt][nt] = __builtin_amdgcn_mfma_f32_16x16x32_bf16(
              a[mt][k], bfr[PAR][nt][k], acc[4 + mt][nt], 0, 0, 0);
  };

#pragma unroll 1
  for (int W = 0; W < 5; ++W) {   // tiles 0..29 in 5 windows of 6
    kstep(ic<0>{}, ic<0>{});
    kstep(ic<1>{}, ic<0>{});
    kstep(ic<2>{}, ic<0>{});
    kstep(ic<3>{}, ic<0>{});
    kstep(ic<4>{}, ic<0>{});
    kstep(ic<5>{}, ic<0>{});
    asrc0 += 768;
#pragma unroll
    for (int nt = 0; nt < 4; ++nt) baddr[nt] += 768;
  }
  kstep(ic<0>{}, ic<1>{});   // t=30: slot0, PAR0; prefetch B(31); no stage
  kstep(ic<1>{}, ic<2>{});   // t=31: slot1, PAR1; no issues

  // ---- Epilogue: 16x16 C/D layout col=lane&15, row=(lane>>4)*4+reg ----
  const float alpha = alpha_p[0];
  const int rbase = bm * 256 + wm * 128 + q * 4;
  const int cbase = bn * 256 + wn * 64 + r15;
#pragma unroll
  for (int mt = 0; mt < 8; ++mt)
#pragma unroll
    for (int nt = 0; nt < 4; ++nt)
#pragma unroll
      for (int r = 0; r < 4; ++r)
        C[(size_t)(rbase + mt * 16 + r) * N_DIM + cbase + nt * 16] =
            alpha * acc[mt][nt][r];
}

// ---- Workspace-free fallback (round-1 verified structure, f32 reg-staged) ----
__global__ __launch_bounds__(256) void gemm_fallback(const float* __restrict__ Ap,
                                                     const float* __restrict__ Bp,
                                                     const float* __restrict__ alpha_p,
                                                     float* __restrict__ C) {
  __shared__ bf16_t Asf[128 * 32];
  __shared__ bf16_t Bsf[128 * 32];
  const int tid = threadIdx.x;
  const int lane = tid & 63;
  const int wid = tid >> 6;
  const int wr = wid >> 1;
  const int wc = wid & 1;
  const int cpx = gridDim.x >> 3;
  const int bid = blockIdx.x;
  const int swz = (bid & 7) * cpx + (bid >> 3);
  const int NB = N_DIM / 128;
  const int bm = swz / NB;
  const int bn = swz % NB;
  f32x4 acc[4][4];
#pragma unroll
  for (int m = 0; m < 4; ++m)
#pragma unroll
    for (int n = 0; n < 4; ++n) acc[m][n] = (f32x4){0.f, 0.f, 0.f, 0.f};
  const int r0 = lane & 15;
  const int ko = (lane >> 4) * 8;
  for (int kk = 0; kk < K_DIM; kk += 32) {
    const float* Af = Ap + (size_t)bm * 128 * K_DIM + kk;
    const float* Bf = Bp + (size_t)bn * 128 * K_DIM + kk;
#pragma unroll
    for (int qq = 0; qq < 4; ++qq) {
      int e = qq * 256 + tid;
      int row = e >> 3;
      int kc = (e & 7) << 2;
      float4 v = *(const float4*)(Af + (size_t)row * K_DIM + kc);
      bf16x4 tv;
      tv[0] = (bf16_t)v.x; tv[1] = (bf16_t)v.y; tv[2] = (bf16_t)v.z; tv[3] = (bf16_t)v.w;
      *(bf16x4*)&Asf[e * 4] = tv;
    }
#pragma unroll
    for (int qq = 0; qq < 4; ++qq) {
      int e = qq * 256 + tid;
      int row = e >> 3;
      int kc = (e & 7) << 2;
      float4 v = *(const float4*)(Bf + (size_t)row * K_DIM + kc);
      float s[4] = {v.x, v.y, v.z, v.w};
      bf16x4 tv;
#pragma unroll
      for (int j = 0; j < 4; ++j)
        tv[j] = (bf16_t)((s[j] > 0.f) ? 1.f : ((s[j] < 0.f) ? -1.f : 0.f));
      *(bf16x4*)&Bsf[e * 4] = tv;
    }
    __syncthreads();
    bf16x8 a[4], b[4];
#pragma unroll
    for (int m = 0; m < 4; ++m) a[m] = *(const bf16x8*)&Asf[(wr * 64 + m * 16 + r0) * 32 + ko];
#pragma unroll
    for (int n = 0; n < 4; ++n) b[n] = *(const bf16x8*)&Bsf[(wc * 64 + n * 16 + r0) * 32 + ko];
#pragma unroll
    for (int m = 0; m < 4; ++m)
#pragma unroll
      for (int n = 0; n < 4; ++n)
        acc[m][n] = __builtin_amdgcn_mfma_f32_16x16x32_bf16(a[m], b[n], acc[m][n], 0, 0, 0);
    __syncthreads();
  }
  const float alpha = alpha_p[0];
  const int rowb = bm * 128 + wr * 64 + (lane >> 4) * 4;
  const int colb = bn * 128 + wc * 64 + r0;
#pragma unroll
  for (int m = 0; m < 4; ++m)
#pragma unroll
    for (int n = 0; n < 4; ++n)
#pragma unroll
      for (int r = 0; r < 4; ++r)
        C[(size_t)(rowb + m * 16 + r) * N_DIM + colb + n * 16] = alpha * acc[m][n][r];
}

extern "C" void kernel_launch(void* const* d_in, const int* in_sizes, int n_in,
                              void* d_out, int out_size, void* d_ws, size_t ws_size,
                              hipStream_t stream) {
  const float* x = (const float*)d_in[0];
  const float* w = (const float*)d_in[1];
  const float* alpha = (const float*)d_in[2];
  float* out = (float*)d_out;

  const size_t nx = (size_t)M_DIM * K_DIM;
  const size_t nw = (size_t)N_DIM * K_DIM;
  const size_t need = (nx + nw) * sizeof(bf16_t);

  if (ws_size >= need) {
    bf16_t* xb = (bf16_t*)d_ws;
    bf16_t* wb = xb + nx;
    cvt_kernel<false><<<(int)(nx / 2048), 256, 0, stream>>>(x, xb);
    cvt_kernel<true><<<(int)(nw / 2048), 256, 0, stream>>>(w, wb);
    (void)hipFuncSetAttribute((const void*)gemm_bg,
                              hipFuncAttributeMaxDynamicSharedMemorySize, 98304);
    gemm_bg<<<512, 512, 98304, stream>>>(xb, wb, alpha, out);
  } else {
    gemm_fallback<<<(M_DIM / 128) * (N_DIM / 128), 256, 0, stream>>>(x, w, alpha, out);
  }
}